// Round 2
// baseline (10648.067 us; speedup 1.0000x reference)
//
#include <hip/hip_runtime.h>
#include <stdint.h>

typedef __attribute__((ext_vector_type(8))) short short8;
typedef __attribute__((ext_vector_type(4))) float floatx4;

static constexpr int kB = 64, kS = 512, kN = 2048;

// ---- workspace layout (bytes) ----
static constexpr size_t RS_OFF     = 0;                     // float rs[kS][kB]
static constexpr size_t RS_BYTES   = (size_t)kS * kB * 4;   // 131072
static constexpr size_t CTR_OFF    = RS_OFF + RS_BYTES;     // 131072
static constexpr size_t CTR_BYTES  = 4 * 513 * 4;           // 8208 (4 domains x 513 slots)
static constexpr size_t EBUF_OFF   = 139392;                // ushort ebuf[2][kB][kN] (bf16 bits)
static constexpr size_t EBUF_BYTES = (size_t)2 * kB * kN * 2;

__device__ __forceinline__ unsigned short f2bf(float x) {
    unsigned u = __builtin_bit_cast(unsigned, x);
    u = (u + 0x7fffu + ((u >> 16) & 1u)) >> 16;   // RNE fp32 -> bf16
    return (unsigned short)u;
}

// Step-indexed arrival barrier across `count` blocks sharing counter `slot`.
// Release ordering on the add publishes this block's stores (L2 writeback to
// coherence point); acquire on the observing load invalidates stale lines
// before we read other blocks' e-tiles/rowsums. __builtin_amdgcn_fence is the
// clang builtin behind the (absent-here) __hip_atomic_fence wrapper.
__device__ __forceinline__ void domain_barrier(unsigned* slot, unsigned count) {
    __syncthreads();  // drains vmcnt: all block stores/atomics acked
    if (threadIdx.x == 0) {
        __builtin_amdgcn_fence(__ATOMIC_RELEASE, "agent");
        __hip_atomic_fetch_add(slot, 1u, __ATOMIC_RELEASE, __HIP_MEMORY_SCOPE_AGENT);
        while (__hip_atomic_load(slot, __ATOMIC_ACQUIRE, __HIP_MEMORY_SCOPE_AGENT) < count)
            __builtin_amdgcn_s_sleep(1);
        __builtin_amdgcn_fence(__ATOMIC_ACQUIRE, "agent");
    }
    __syncthreads();
}

// ================== main kernel: 256 blocks x 256 thr, 139 KiB LDS ==================
// Block (bg,cg): batch rows [bg*16,+16), cols [cg*32,+32). Domain = bg (64 blocks).
// W_rec slice lives in LDS in MFMA B-fragment order for the whole kernel.
__global__ __launch_bounds__(256) void pcn_big(
    const float* __restrict__ vel, const float* __restrict__ h0,
    const float* __restrict__ Wlin, const float* __restrict__ blin,
    const float* __restrict__ Wrec, float* __restrict__ out,
    float* rs, unsigned* ctr, unsigned short* ebuf)
{
    extern __shared__ char smem[];
    short8* Wlds = (short8*)smem;            // [64 kt][2 ct][64 lanes] = 128 KiB
    float*  red  = (float*)(smem + 131072);  // [4 waves][512 cells]   = 8 KiB

    const int tid  = threadIdx.x;
    const int lane = tid & 63;
    const int w    = tid >> 6;
    const int bg   = blockIdx.x >> 6;   // 0..3   (barrier domain)
    const int cg   = blockIdx.x & 63;   // 0..63
    const int b0   = bg * 16;
    const int c0   = cg * 32;
    const int koff = (lane >> 4) << 3;  // quad*8: k-offset of this lane's fragment

    // ---- one-time: stage W_rec[k, c0..c0+31] into LDS, B-fragment order ----
    // B-frag (16x16x32): lane holds B[k = kt*32 + quad*8 + j][n = lane&15]
    for (int kt = w * 16; kt < w * 16 + 16; ++kt) {
        for (int ct = 0; ct < 2; ++ct) {
            const int colg = c0 + ct * 16 + (lane & 15);
            const int kb   = kt * 32 + koff;
            short8 v;
            #pragma unroll
            for (int j = 0; j < 8; ++j)
                v[j] = (short)f2bf(Wrec[(size_t)(kb + j) * kN + colg]);
            Wlds[(kt * 2 + ct) * 64 + lane] = v;
        }
    }

    const int r  = tid >> 4;        // 0..15: row in tile (epilogue mapping)
    const int cc = (tid & 15) * 2;  // 0..30: even col in tile (2 adjacent cols/thread)

    // init read-buffer (index 1) with bf16(h0); step 0 uses s_inv = 1
    {
        const float a0 = h0[(size_t)(b0 + r) * kN + c0 + cc];
        const float a1 = h0[(size_t)(b0 + r) * kN + c0 + cc + 1];
        const unsigned pk = (unsigned)f2bf(a0) | ((unsigned)f2bf(a1) << 16);
        *(unsigned*)(ebuf + (size_t)kB * kN + (size_t)(b0 + r) * kN + c0 + cc) = pk;
    }

    // per-thread logits coefficients for its 2 columns
    const float wl00 = Wlin[(c0 + cc) * 2 + 0],     wl01 = Wlin[(c0 + cc) * 2 + 1];
    const float wl10 = Wlin[(c0 + cc + 1) * 2 + 0], wl11 = Wlin[(c0 + cc + 1) * 2 + 1];
    const float bl0  = blin[c0 + cc], bl1 = blin[c0 + cc + 1];

    domain_barrier(ctr + bg * 513 + 512, 64);   // init fence for e-buffer

    float s_inv = 1.0f;           // 1/rowsum of previous step (h0: unnormalized, s=1)
    float ep0 = 0.0f, ep1 = 0.0f; // previous step's unnormalized e (this thread's 2 cells)
    const int arow = b0 + (lane & 15);   // A-frag row

    for (int t = 0; t < kS; ++t) {
        // ---- GEMM: g = e_{t-1} @ Wslice ; wave w covers kt in [w*16, w*16+16) ----
        const unsigned short* ebR = ebuf + (size_t)((t + 1) & 1) * kB * kN;
        floatx4 acc0 = {0.f,0.f,0.f,0.f}, acc1 = {0.f,0.f,0.f,0.f};
        #pragma unroll
        for (int kt = 0; kt < 16; ++kt) {
            const int ktg = w * 16 + kt;
            const short8 a   = *(const short8*)(ebR + (size_t)arow * kN + ktg * 32 + koff);
            const short8 bq0 = Wlds[(ktg * 2 + 0) * 64 + lane];
            const short8 bq1 = Wlds[(ktg * 2 + 1) * 64 + lane];
            acc0 = __builtin_amdgcn_mfma_f32_16x16x32_bf16(a, bq0, acc0, 0, 0, 0);
            acc1 = __builtin_amdgcn_mfma_f32_16x16x32_bf16(a, bq1, acc1, 0, 0, 0);
        }
        // stage partials: C/D layout col=lane&15, row=quad*4+i
        {
            const int ccol = lane & 15, crow = (lane >> 4) * 4;
            #pragma unroll
            for (int i = 0; i < 4; ++i) {
                red[w * 512 + (crow + i) * 32 + ccol]      = acc0[i];
                red[w * 512 + (crow + i) * 32 + 16 + ccol] = acc1[i];
            }
        }
        __syncthreads();
        float g0 = 0.f, g1 = 0.f;
        {
            const int cell = tid * 2;   // cell = r*32 + c
            #pragma unroll
            for (int ww = 0; ww < 4; ++ww) {
                g0 += red[ww * 512 + cell];
                g1 += red[ww * 512 + cell + 1];
            }
        }
        // ---- epilogue: z = base_logits + g/s_prev ; e = exp(z) (no max needed, |z|<~2.5)
        const float v0 = vel[((size_t)(b0 + r) * kS + t) * 2 + 0];
        const float v1 = vel[((size_t)(b0 + r) * kS + t) * 2 + 1];
        const float z0 = fmaf(g0, s_inv, fmaf(v0, wl00, fmaf(v1, wl01, bl0)));
        const float z1 = fmaf(g1, s_inv, fmaf(v0, wl10, fmaf(v1, wl11, bl1)));
        const float e0 = __expf(z0), e1 = __expf(z1);

        // row-sum of this block's 32 cols (16 threads per row, within one wave)
        float es = e0 + e1;
        es += __shfl_xor(es, 8, 16);
        es += __shfl_xor(es, 4, 16);
        es += __shfl_xor(es, 2, 16);
        es += __shfl_xor(es, 1, 16);
        if ((lane & 15) == 0) atomicAdd(&rs[t * kB + b0 + r], es);

        // store unnormalized e_t (bf16 pair) into write buffer
        const unsigned pk = (unsigned)f2bf(e0) | ((unsigned)f2bf(e1) << 16);
        *(unsigned*)(ebuf + (size_t)(t & 1) * kB * kN + (size_t)(b0 + r) * kN + c0 + cc) = pk;

        // write previous step's normalized output (full fp32 from registers)
        if (t > 0) {
            float2 o; o.x = ep0 * s_inv; o.y = ep1 * s_inv;
            *(float2*)(out + ((size_t)(b0 + r) * kS + (t - 1)) * kN + c0 + cc) = o;
        }
        ep0 = e0; ep1 = e1;

        domain_barrier(ctr + bg * 513 + t, 64);  // e_t + rs[t] now globally visible
        const float s = __hip_atomic_load(&rs[t * kB + b0 + r],
                                          __ATOMIC_RELAXED, __HIP_MEMORY_SCOPE_AGENT);
        s_inv = 1.0f / s;
    }
    {   // final output row t = 511
        float2 o; o.x = ep0 * s_inv; o.y = ep1 * s_inv;
        *(float2*)(out + ((size_t)(b0 + r) * kS + (kS - 1)) * kN + c0 + cc) = o;
    }
}

// ============ fallback kernel: 512 blocks x 64 thr, exactly 64 KiB static LDS ============
// Tile 16x16, single wave, no cross-wave reduce. Domain = bg (128 blocks).
__global__ __launch_bounds__(64) void pcn_small(
    const float* __restrict__ vel, const float* __restrict__ h0,
    const float* __restrict__ Wlin, const float* __restrict__ blin,
    const float* __restrict__ Wrec, float* __restrict__ out,
    float* rs, unsigned* ctr, unsigned short* ebuf)
{
    __shared__ short8 Wlds[64 * 64];   // 64 KiB: [64 kt][64 lanes]
    const int lane = threadIdx.x;
    const int bg = blockIdx.x >> 7;    // 0..3
    const int cg = blockIdx.x & 127;   // 0..127
    const int b0 = bg * 16;
    const int c0 = cg * 16;
    const int koff = (lane >> 4) << 3;
    const int col  = lane & 15;
    const int rq   = (lane >> 4) * 4;  // C/D row base for this lane

    for (int kt = 0; kt < 64; ++kt) {
        const int kb = kt * 32 + koff;
        short8 v;
        #pragma unroll
        for (int j = 0; j < 8; ++j)
            v[j] = (short)f2bf(Wrec[(size_t)(kb + j) * kN + c0 + col]);
        Wlds[kt * 64 + lane] = v;
    }
    #pragma unroll
    for (int i = 0; i < 4; ++i) {
        const int rr = b0 + rq + i;
        ebuf[(size_t)kB * kN + (size_t)rr * kN + c0 + col] = f2bf(h0[(size_t)rr * kN + c0 + col]);
    }
    const float wl0 = Wlin[(c0 + col) * 2 + 0], wl1 = Wlin[(c0 + col) * 2 + 1];
    const float bl  = blin[c0 + col];

    domain_barrier(ctr + bg * 513 + 512, 128);

    float sinv[4] = {1.f, 1.f, 1.f, 1.f};
    float ep[4]   = {0.f, 0.f, 0.f, 0.f};
    const int arow = b0 + col;

    for (int t = 0; t < kS; ++t) {
        const unsigned short* ebR = ebuf + (size_t)((t + 1) & 1) * kB * kN;
        floatx4 a0 = {0.f,0.f,0.f,0.f}, a1 = {0.f,0.f,0.f,0.f};
        #pragma unroll 8
        for (int kt = 0; kt < 64; kt += 2) {
            const short8 x0 = *(const short8*)(ebR + (size_t)arow * kN + kt * 32 + koff);
            const short8 x1 = *(const short8*)(ebR + (size_t)arow * kN + (kt + 1) * 32 + koff);
            a0 = __builtin_amdgcn_mfma_f32_16x16x32_bf16(x0, Wlds[kt * 64 + lane], a0, 0, 0, 0);
            a1 = __builtin_amdgcn_mfma_f32_16x16x32_bf16(x1, Wlds[(kt + 1) * 64 + lane], a1, 0, 0, 0);
        }
        const floatx4 g = a0 + a1;
        float e[4];
        #pragma unroll
        for (int i = 0; i < 4; ++i) {
            const int rr = b0 + rq + i;
            const float vv0 = vel[((size_t)rr * kS + t) * 2 + 0];
            const float vv1 = vel[((size_t)rr * kS + t) * 2 + 1];
            const float z = fmaf(g[i], sinv[i], fmaf(vv0, wl0, fmaf(vv1, wl1, bl)));
            e[i] = __expf(z);
        }
        #pragma unroll
        for (int i = 0; i < 4; ++i) {
            float s = e[i];
            s += __shfl_xor(s, 8, 16);
            s += __shfl_xor(s, 4, 16);
            s += __shfl_xor(s, 2, 16);
            s += __shfl_xor(s, 1, 16);
            if (col == 0) atomicAdd(&rs[t * kB + b0 + rq + i], s);
        }
        unsigned short* ebW = ebuf + (size_t)(t & 1) * kB * kN;
        #pragma unroll
        for (int i = 0; i < 4; ++i) {
            const int rr = b0 + rq + i;
            ebW[(size_t)rr * kN + c0 + col] = f2bf(e[i]);
            if (t > 0) out[((size_t)rr * kS + (t - 1)) * kN + c0 + col] = ep[i] * sinv[i];
            ep[i] = e[i];
        }
        domain_barrier(ctr + bg * 513 + t, 128);
        #pragma unroll
        for (int i = 0; i < 4; ++i) {
            const float s = __hip_atomic_load(&rs[t * kB + b0 + rq + i],
                                              __ATOMIC_RELAXED, __HIP_MEMORY_SCOPE_AGENT);
            sinv[i] = 1.0f / s;
        }
    }
    #pragma unroll
    for (int i = 0; i < 4; ++i) {
        const int rr = b0 + rq + i;
        out[((size_t)rr * kS + (kS - 1)) * kN + c0 + col] = ep[i] * sinv[i];
    }
}

extern "C" void kernel_launch(void* const* d_in, const int* in_sizes, int n_in,
                              void* d_out, int out_size, void* d_ws, size_t ws_size,
                              hipStream_t stream)
{
    (void)in_sizes; (void)n_in; (void)out_size; (void)ws_size;
    const float* vel  = (const float*)d_in[0];
    const float* h0   = (const float*)d_in[1];
    const float* Wlin = (const float*)d_in[2];
    const float* blin = (const float*)d_in[3];
    const float* Wrec = (const float*)d_in[4];
    float* out = (float*)d_out;

    char* ws = (char*)d_ws;
    float* rs            = (float*)(ws + RS_OFF);
    unsigned* ctr        = (unsigned*)(ws + CTR_OFF);
    unsigned short* ebuf = (unsigned short*)(ws + EBUF_OFF);

    // rowsums + barrier counters must start at 0 (ws is poisoned 0xAA each launch)
    (void)hipMemsetAsync(ws, 0, CTR_OFF + CTR_BYTES, stream);

    const unsigned smem_big = 131072 + 8192;   // 139264 B dynamic LDS
    hipError_t attr_err = hipFuncSetAttribute((const void*)pcn_big,
        hipFuncAttributeMaxDynamicSharedMemorySize, (int)smem_big);

    bool launched = false;
    if (attr_err == hipSuccess) {
        void* args[] = { (void*)&vel, (void*)&h0, (void*)&Wlin, (void*)&blin,
                         (void*)&Wrec, (void*)&out, (void*)&rs, (void*)&ctr, (void*)&ebuf };
        hipError_t err = hipLaunchCooperativeKernel((const void*)pcn_big,
            dim3(256), dim3(256), args, smem_big, stream);
        if (err == hipSuccess) {
            launched = true;
        } else {
            (void)hipGetLastError();
            // plain launch: 256 blocks @ 1 block/CU are co-resident by capacity
            hipLaunchKernelGGL(pcn_big, dim3(256), dim3(256), smem_big, stream,
                               vel, h0, Wlin, blin, Wrec, out, rs, ctr, ebuf);
            if (hipGetLastError() == hipSuccess) launched = true;
        }
    }
    if (!launched) {
        (void)hipGetLastError();
        // last-ditch: 64 KiB-LDS variant, 512 blocks @ 2 blocks/CU co-resident
        hipLaunchKernelGGL(pcn_small, dim3(512), dim3(64), 0, stream,
                           vel, h0, Wlin, blin, Wrec, out, rs, ctr, ebuf);
    }
}

// Round 3
// 2716.106 us; speedup vs baseline: 3.9203x; 3.9203x over previous
//
#include <hip/hip_runtime.h>
#include <stdint.h>

typedef __attribute__((ext_vector_type(8))) short short8;
typedef __attribute__((ext_vector_type(4))) float floatx4;

static constexpr int kB = 64, kS = 512, kN = 2048;

// ---- workspace layout (bytes) ----
// ctr: 4 domains x 513 step-indexed barrier counters (write-once per launch)
static constexpr size_t CTR_OFF        = 0;
static constexpr size_t CTR_BYTES      = 4 * 513 * 4;                      // 8208
static constexpr size_t RSP_OFF        = 16384;                            // rowsum partials
static constexpr size_t RSP_BYTES_BIG  = (size_t)kS * 4 * 16 * 64 * 4;     // [t][bg][r][cg] = 8 MiB
static constexpr size_t RSP_BYTES_SM   = (size_t)2 * 4 * 16 * 64 * 4;      // parity mode: 32 KiB
static constexpr size_t SLAB           = (size_t)kB * kN * 2;              // one e-slab: 256 KiB
static constexpr size_t EBUF_OFF_BIG   = RSP_OFF + RSP_BYTES_BIG;
static constexpr size_t TOTAL_BIG      = EBUF_OFF_BIG + 513 * SLAB;        // ~136.3 MiB
static constexpr size_t EBUF_OFF_SM    = RSP_OFF + RSP_BYTES_SM;
static constexpr size_t TOTAL_SM       = EBUF_OFF_SM + 2 * SLAB;           // ~0.55 MiB

__device__ __forceinline__ unsigned short f2bf(float x) {
    unsigned u = __builtin_bit_cast(unsigned, x);
    u = (u + 0x7fffu + ((u >> 16) & 1u)) >> 16;   // RNE fp32 -> bf16
    return (unsigned short)u;
}

// Bare arrival barrier: NO cache-wide fences (agent-scope fences on gfx950 lower
// to buffer_wbl2/buffer_inv = full L2 writeback+invalidate per call — that was
// 21us/step in round 2). Correctness: all cross-block data is published with
// agent-scope (sc0/sc1) stores that reach the coherence point before the
// __syncthreads vmcnt(0) drain; the counter bump happens after in real time,
// and observers' post-spin loads issue only after the spin branch resolves.
__device__ __forceinline__ void domain_barrier(unsigned* slot, unsigned count) {
    __syncthreads();   // vmcnt(0): coherent stores acked at coherence point
    if (threadIdx.x == 0) {
        __hip_atomic_fetch_add(slot, 1u, __ATOMIC_RELAXED, __HIP_MEMORY_SCOPE_AGENT);
        while (__hip_atomic_load(slot, __ATOMIC_RELAXED, __HIP_MEMORY_SCOPE_AGENT) < count)
            __builtin_amdgcn_s_sleep(1);
    }
    __syncthreads();
}

struct ULL2 { unsigned long long lo, hi; };

// ================== 256 blocks x 256 thr, 139 KiB LDS, 1 block/CU ==================
// Domain bg (batch rows bg*16..+16) = 64 blocks on XCD pair {2bg,2bg+1} (blk%8 swizzle).
// BIG: write-once e-slabs/rowsum-partials -> plain cached consumer loads.
// !BIG: 2-slab parity -> agent-scope (cache-bypassing) consumer loads.
template<bool BIG>
__global__ __launch_bounds__(256) void pcn(
    const float* __restrict__ vel, const float* __restrict__ h0,
    const float* __restrict__ Wlin, const float* __restrict__ blin,
    const float* __restrict__ Wrec, float* __restrict__ out,
    float* rsp, unsigned* ctr, unsigned short* ebuf)
{
    extern __shared__ char smem[];
    short8* Wlds = (short8*)smem;            // [64 kt][2 ct][64 lanes] = 128 KiB
    float*  red  = (float*)(smem + 131072);  // [4 waves][512 cells]   = 8 KiB

    const int tid  = threadIdx.x;
    const int lane = tid & 63;
    const int w    = tid >> 6;
    // XCD swizzle (XCD = blockIdx%8 heuristic): domain bg on XCDs {2bg, 2bg+1}
    const int bg   = (blockIdx.x & 7) >> 1;                       // 0..3
    const int cg   = ((blockIdx.x >> 3) << 1) | (blockIdx.x & 1); // 0..63
    const int b0   = bg * 16;
    const int c0   = cg * 32;
    const int koff = (lane >> 4) << 3;  // quad*8: k-offset of this lane's A/B fragment

    // ---- one-time: stage W_rec[k, c0..c0+31] into LDS, B-fragment order ----
    for (int kt = w * 16; kt < w * 16 + 16; ++kt) {
        for (int ct = 0; ct < 2; ++ct) {
            const int colg = c0 + ct * 16 + (lane & 15);
            const int kb   = kt * 32 + koff;
            short8 v;
            #pragma unroll
            for (int j = 0; j < 8; ++j)
                v[j] = (short)f2bf(Wrec[(size_t)(kb + j) * kN + colg]);
            Wlds[(kt * 2 + ct) * 64 + lane] = v;
        }
    }

    const int r   = tid >> 4;        // 0..15: row in tile
    const int c16 = tid & 15;
    const int cc  = c16 * 2;         // even col in tile (2 adjacent cols/thread)

    // h0 -> slab 0 (published with agent-scope store)
    {
        const float a0 = h0[(size_t)(b0 + r) * kN + c0 + cc];
        const float a1 = h0[(size_t)(b0 + r) * kN + c0 + cc + 1];
        const unsigned pk = (unsigned)f2bf(a0) | ((unsigned)f2bf(a1) << 16);
        __hip_atomic_store((unsigned*)(ebuf + (size_t)(b0 + r) * kN + c0 + cc), pk,
                           __ATOMIC_RELAXED, __HIP_MEMORY_SCOPE_AGENT);
    }

    const float wl00 = Wlin[(c0 + cc) * 2 + 0],     wl01 = Wlin[(c0 + cc) * 2 + 1];
    const float wl10 = Wlin[(c0 + cc + 1) * 2 + 0], wl11 = Wlin[(c0 + cc + 1) * 2 + 1];
    const float bl0  = blin[c0 + cc], bl1 = blin[c0 + cc + 1];

    domain_barrier(ctr + bg * 513 + 512, 64);   // h0 slab published

    float s_inv = 1.0f;           // 1/rowsum of previous step (h0: s = 1)
    float ep0 = 0.0f, ep1 = 0.0f; // previous step's unnormalized e
    const int arow = b0 + (lane & 15);

    for (int t = 0; t < kS; ++t) {
        const int rslot = BIG ? t       : (t & 1);
        const int wslot = BIG ? (t + 1) : ((t + 1) & 1);
        const unsigned short* ebR = ebuf + (size_t)rslot * (kB * kN);

        // ---- GEMM: g = e_{t-1} @ Wslice ; wave w covers kt in [w*16, +16) ----
        floatx4 acc0 = {0.f,0.f,0.f,0.f}, acc1 = {0.f,0.f,0.f,0.f};
        #pragma unroll
        for (int kt = 0; kt < 16; ++kt) {
            const int ktg = w * 16 + kt;
            const unsigned short* ap = ebR + (size_t)arow * kN + ktg * 32 + koff;
            short8 a;
            if (BIG) {
                a = *(const short8*)ap;   // write-once region: plain cached load safe
            } else {
                ULL2 u;
                u.lo = __hip_atomic_load((const unsigned long long*)ap,
                                         __ATOMIC_RELAXED, __HIP_MEMORY_SCOPE_AGENT);
                u.hi = __hip_atomic_load((const unsigned long long*)ap + 1,
                                         __ATOMIC_RELAXED, __HIP_MEMORY_SCOPE_AGENT);
                a = __builtin_bit_cast(short8, u);
            }
            const short8 bq0 = Wlds[(ktg * 2 + 0) * 64 + lane];
            const short8 bq1 = Wlds[(ktg * 2 + 1) * 64 + lane];
            acc0 = __builtin_amdgcn_mfma_f32_16x16x32_bf16(a, bq0, acc0, 0, 0, 0);
            acc1 = __builtin_amdgcn_mfma_f32_16x16x32_bf16(a, bq1, acc1, 0, 0, 0);
        }
        // cross-wave reduce via LDS (C/D layout: col=lane&15, row=quad*4+i)
        {
            const int ccol = lane & 15, crow = (lane >> 4) * 4;
            #pragma unroll
            for (int i = 0; i < 4; ++i) {
                red[w * 512 + (crow + i) * 32 + ccol]      = acc0[i];
                red[w * 512 + (crow + i) * 32 + 16 + ccol] = acc1[i];
            }
        }
        __syncthreads();
        float g0 = 0.f, g1 = 0.f;
        {
            const int cell = tid * 2;
            #pragma unroll
            for (int ww = 0; ww < 4; ++ww) {
                g0 += red[ww * 512 + cell];
                g1 += red[ww * 512 + cell + 1];
            }
        }

        // ---- epilogue: z = base_logits + g/s_prev ; e = exp(z) ----
        const float v0 = vel[((size_t)(b0 + r) * kS + t) * 2 + 0];
        const float v1 = vel[((size_t)(b0 + r) * kS + t) * 2 + 1];
        const float z0 = fmaf(g0, s_inv, fmaf(v0, wl00, fmaf(v1, wl01, bl0)));
        const float z1 = fmaf(g1, s_inv, fmaf(v0, wl10, fmaf(v1, wl11, bl1)));
        const float e0 = __expf(z0), e1 = __expf(z1);

        // local 32-col row-sum (16 threads/row, intra-wave)
        float es = e0 + e1;
        es += __shfl_xor(es, 8, 16);
        es += __shfl_xor(es, 4, 16);
        es += __shfl_xor(es, 2, 16);
        es += __shfl_xor(es, 1, 16);
        // one partial-sum store per row per block — NO atomicAdd hotspot
        if (c16 == 0) {
            const size_t pidx = (((size_t)rslot * 4 + bg) * 16 + r) * 64 + cg;
            __hip_atomic_store(rsp + pidx, es, __ATOMIC_RELAXED, __HIP_MEMORY_SCOPE_AGENT);
        }

        // publish unnormalized e_t (bf16 pair, agent-scope 4B store)
        {
            const unsigned pk = (unsigned)f2bf(e0) | ((unsigned)f2bf(e1) << 16);
            __hip_atomic_store(
                (unsigned*)(ebuf + (size_t)wslot * (kB * kN) + (size_t)(b0 + r) * kN + c0 + cc),
                pk, __ATOMIC_RELAXED, __HIP_MEMORY_SCOPE_AGENT);
        }

        // previous step's normalized output (plain store; flushed at kernel end)
        if (t > 0) {
            float2 o; o.x = ep0 * s_inv; o.y = ep1 * s_inv;
            *(float2*)(out + ((size_t)(b0 + r) * kS + (t - 1)) * kN + c0 + cc) = o;
        }
        ep0 = e0; ep1 = e1;

        domain_barrier(ctr + bg * 513 + t, 64);  // e_t + partials now visible

        // reduce 64 rowsum partials: 4 loads + 4 shuffles per thread
        {
            const float* rp = rsp + (((size_t)rslot * 4 + bg) * 16 + r) * 64 + c16 * 4;
            float s;
            if (BIG) {
                const floatx4 v = *(const floatx4*)rp;   // write-once: plain load safe
                s = (v[0] + v[1]) + (v[2] + v[3]);
            } else {
                float p0 = __hip_atomic_load(rp + 0, __ATOMIC_RELAXED, __HIP_MEMORY_SCOPE_AGENT);
                float p1 = __hip_atomic_load(rp + 1, __ATOMIC_RELAXED, __HIP_MEMORY_SCOPE_AGENT);
                float p2 = __hip_atomic_load(rp + 2, __ATOMIC_RELAXED, __HIP_MEMORY_SCOPE_AGENT);
                float p3 = __hip_atomic_load(rp + 3, __ATOMIC_RELAXED, __HIP_MEMORY_SCOPE_AGENT);
                s = (p0 + p1) + (p2 + p3);
            }
            s += __shfl_xor(s, 8, 16);
            s += __shfl_xor(s, 4, 16);
            s += __shfl_xor(s, 2, 16);
            s += __shfl_xor(s, 1, 16);
            s_inv = 1.0f / s;
        }
    }
    {   // final output row t = 511
        float2 o; o.x = ep0 * s_inv; o.y = ep1 * s_inv;
        *(float2*)(out + ((size_t)(b0 + r) * kS + (kS - 1)) * kN + c0 + cc) = o;
    }
}

extern "C" void kernel_launch(void* const* d_in, const int* in_sizes, int n_in,
                              void* d_out, int out_size, void* d_ws, size_t ws_size,
                              hipStream_t stream)
{
    (void)in_sizes; (void)n_in; (void)out_size;
    const float* vel  = (const float*)d_in[0];
    const float* h0   = (const float*)d_in[1];
    const float* Wlin = (const float*)d_in[2];
    const float* blin = (const float*)d_in[3];
    const float* Wrec = (const float*)d_in[4];
    float* out = (float*)d_out;

    char* ws = (char*)d_ws;
    unsigned* ctr = (unsigned*)(ws + CTR_OFF);
    const bool big = ws_size >= TOTAL_BIG;
    float* rsp            = (float*)(ws + RSP_OFF);
    unsigned short* ebuf  = (unsigned short*)(ws + (big ? EBUF_OFF_BIG : EBUF_OFF_SM));

    // only the barrier counters need zeroing (ws is poisoned 0xAA each launch;
    // rsp/ebuf are fully written before first read)
    (void)hipMemsetAsync(ws + CTR_OFF, 0, CTR_BYTES, stream);

    const unsigned smem = 131072 + 8192;   // 139264 B dynamic LDS -> 1 block/CU
    const void* fn = big ? (const void*)pcn<true> : (const void*)pcn<false>;
    (void)hipFuncSetAttribute(fn, hipFuncAttributeMaxDynamicSharedMemorySize, (int)smem);

    void* args[] = { (void*)&vel, (void*)&h0, (void*)&Wlin, (void*)&blin,
                     (void*)&Wrec, (void*)&out, (void*)&rsp, (void*)&ctr, (void*)&ebuf };
    hipError_t err = hipLaunchCooperativeKernel(fn, dim3(256), dim3(256), args, smem, stream);
    if (err != hipSuccess) {
        (void)hipGetLastError();
        // plain launch: 256 blocks @ 1 block/CU are co-resident by capacity
        if (big)
            hipLaunchKernelGGL(pcn<true>, dim3(256), dim3(256), smem, stream,
                               vel, h0, Wlin, blin, Wrec, out, rsp, ctr, ebuf);
        else
            hipLaunchKernelGGL(pcn<false>, dim3(256), dim3(256), smem, stream,
                               vel, h0, Wlin, blin, Wrec, out, rsp, ctr, ebuf);
    }
}